// Round 7
// baseline (1994.276 us; speedup 1.0000x reference)
//
#include <hip/hip_runtime.h>

#define NN 50000
#define EE 600000

__device__ inline void fma4(float4& a, float s, const float4 w) {
  a.x = fmaf(s, w.x, a.x);
  a.y = fmaf(s, w.y, a.y);
  a.z = fmaf(s, w.z, a.z);
  a.w = fmaf(s, w.w, a.w);
}

__device__ inline ushort f2bf(float x) {  // round-to-nearest-even bf16
  unsigned u = __float_as_uint(x);
  u = (u + 0x7fffu + ((u >> 16) & 1u)) >> 16;
  return (ushort)u;
}
__device__ inline float bflo(uint t) { return __uint_as_float(t << 16); }
__device__ inline float bfhi(uint t) { return __uint_as_float(t & 0xffff0000u); }

// ---------- graph preprocessing ----------
__global__ void count2_k(const int* __restrict__ ei, int* __restrict__ cnt_s,
                         int* __restrict__ cnt_d) {
  int e = blockIdx.x * 256 + threadIdx.x;
  if (e < EE) {
    atomicAdd(&cnt_s[ei[e]], 1);
    atomicAdd(&cnt_d[ei[EE + e]], 1);
  }
}

__global__ void scan_k(const int* __restrict__ cnt, int* __restrict__ rs) {
  __shared__ int ls[1024];
  const int t = threadIdx.x;
  const int STRIP = (NN + 1023) >> 10;  // 49
  int i0 = t * STRIP;
  int i1 = min(i0 + STRIP, NN);
  int s = 0;
  for (int i = i0; i < i1; ++i) s += cnt[i];
  ls[t] = s;
  __syncthreads();
  for (int off = 1; off < 1024; off <<= 1) {
    int v = (t >= off) ? ls[t - off] : 0;
    __syncthreads();
    ls[t] += v;
    __syncthreads();
  }
  int run = (t == 0) ? 0 : ls[t - 1];
  for (int i = i0; i < i1; ++i) { rs[i] = run; run += cnt[i]; }
  if (t == 0) rs[NN] = EE;
}

// big path: CSC order (grouped by src), each edge carries its CSR slot + w
__global__ void fill2_k(const int* __restrict__ ei, const float* __restrict__ ew,
                        int* __restrict__ cur_s, int* __restrict__ cur_d,
                        int* __restrict__ srcs, int2* __restrict__ pw) {
  int e = blockIdx.x * 256 + threadIdx.x;
  if (e < EE) {
    int s = ei[e], d = ei[EE + e];
    int pc = atomicAdd(&cur_s[s], 1);
    int pr = atomicAdd(&cur_d[d], 1);
    srcs[pc] = s;
    int2 v;
    v.x = pr;
    v.y = __float_as_int(ew[e]);
    pw[pc] = v;
  }
}

// fallback path: CSR {src, w}
__global__ void fill_k(const int* __restrict__ ei, const float* __restrict__ ew,
                       int* __restrict__ cur, int2* __restrict__ esw) {
  int e = blockIdx.x * 256 + threadIdx.x;
  if (e < EE) {
    int d = ei[EE + e];
    int p = atomicAdd(&cur[d], 1);
    int2 v;
    v.x = ei[e];
    v.y = __float_as_int(ew[e]);
    esw[p] = v;
  }
}

__global__ void invd_k(const int* __restrict__ rs, float* __restrict__ invd) {
  int n = blockIdx.x * 256 + threadIdx.x;
  if (n < NN) {
    int d = rs[n + 1] - rs[n];
    invd[n] = 1.0f / (float)max(d, 1);
  }
}

// ---------- fused dual GEMM: Tl(bf16,col-chunked) / Tr(f32) ----------
// Tl layout: chunk c (32 cols) at Tlb + c*NN*32 ushorts.
template <int F>
__global__ __launch_bounds__(256, 3) void gemm_dual(
    const float* __restrict__ H, const float* __restrict__ Wl,
    const float* __restrict__ Wr, const float* __restrict__ ss,
    ushort* __restrict__ Tlb, float* __restrict__ Tr) {
  constexpr int K = 128;
  constexpr int Kc = 32;
  constexpr int TX = F / 4;
  constexpr int TY = 256 / TX;
  constexpr int ROWS = TY * 8;
  constexpr int HS = ROWS + 4;
  __shared__ __align__(16) float Wls[Kc][F];
  __shared__ __align__(16) float Wrs[Kc][F];
  __shared__ __align__(16) float Hs[Kc][HS];
  const int tid = threadIdx.x;
  const int tx = tid % TX, ty = tid / TX;
  const int n0 = blockIdx.x * ROWS;

  const float4 z4 = {0.f, 0.f, 0.f, 0.f};
  float4 aAA[4], aAB[4], aBA[4], aBB[4];
#pragma unroll
  for (int r = 0; r < 4; ++r) { aAA[r] = z4; aAB[r] = z4; aBA[r] = z4; aBB[r] = z4; }

  for (int kc = 0; kc < K; kc += Kc) {
    __syncthreads();
    for (int idx = tid; idx < Kc * (F / 4); idx += 256) {
      int k = idx / (F / 4), c = idx % (F / 4);
      ((float4*)(&Wls[k][0]))[c] = ((const float4*)Wl)[(kc + k) * (F / 4) + c];
      ((float4*)(&Wrs[k][0]))[c] = ((const float4*)Wr)[(kc + k) * (F / 4) + c];
    }
    for (int idx = tid; idx < ROWS * 8; idx += 256) {
      int i = idx >> 3, k4 = idx & 7;
      int nrow = n0 + i;
      float4 hv = z4;
      if (nrow < NN) hv = ((const float4*)H)[nrow * 32 + (kc >> 2) + k4];
      if (ss) {
        int gk = kc + k4 * 4;
        hv.x = fmaxf(fmaf(hv.x, ss[gk + 0], ss[128 + gk + 0]), 0.f);
        hv.y = fmaxf(fmaf(hv.y, ss[gk + 1], ss[128 + gk + 1]), 0.f);
        hv.z = fmaxf(fmaf(hv.z, ss[gk + 2], ss[128 + gk + 2]), 0.f);
        hv.w = fmaxf(fmaf(hv.w, ss[gk + 3], ss[128 + gk + 3]), 0.f);
      }
      Hs[k4 * 4 + 0][i] = hv.x;
      Hs[k4 * 4 + 1][i] = hv.y;
      Hs[k4 * 4 + 2][i] = hv.z;
      Hs[k4 * 4 + 3][i] = hv.w;
    }
    __syncthreads();
#pragma unroll 4
    for (int k = 0; k < Kc; ++k) {
      float4 wA = *(const float4*)&Wls[k][tx * 4];
      float4 wB = *(const float4*)&Wrs[k][tx * 4];
      float4 hA = *(const float4*)&Hs[k][ty * 4];
      float4 hB = *(const float4*)&Hs[k][ROWS / 2 + ty * 4];
      fma4(aAA[0], hA.x, wA); fma4(aAA[1], hA.y, wA); fma4(aAA[2], hA.z, wA); fma4(aAA[3], hA.w, wA);
      fma4(aAB[0], hA.x, wB); fma4(aAB[1], hA.y, wB); fma4(aAB[2], hA.z, wB); fma4(aAB[3], hA.w, wB);
      fma4(aBA[0], hB.x, wA); fma4(aBA[1], hB.y, wA); fma4(aBA[2], hB.z, wA); fma4(aBA[3], hB.w, wA);
      fma4(aBB[0], hB.x, wB); fma4(aBB[1], hB.y, wB); fma4(aBB[2], hB.z, wB); fma4(aBB[3], hB.w, wB);
    }
  }
  float4* Tr4 = (float4*)Tr;
  const int c0 = tx * 4;
  const int chunk = c0 >> 5;
  const int coff = c0 & 31;
#pragma unroll
  for (int r = 0; r < 4; ++r) {
    int nA = n0 + ty * 4 + r;
    if (nA < NN) {
      ushort4 u4 = {f2bf(aAA[r].x), f2bf(aAA[r].y), f2bf(aAA[r].z), f2bf(aAA[r].w)};
      *(ushort4*)(Tlb + (size_t)chunk * NN * 32 + (size_t)nA * 32 + coff) = u4;
      Tr4[(size_t)nA * TX + tx] = aAB[r];
    }
    int nB = n0 + ROWS / 2 + ty * 4 + r;
    if (nB < NN) {
      ushort4 u4 = {f2bf(aBA[r].x), f2bf(aBA[r].y), f2bf(aBA[r].z), f2bf(aBA[r].w)};
      *(ushort4*)(Tlb + (size_t)chunk * NN * 32 + (size_t)nB * 32 + coff) = u4;
      Tr4[(size_t)nB * TX + tx] = aBB[r];
    }
  }
}

// ---------- big path pass 1: CSC-ordered streaming read, scattered write ----
// CP cols per pass; CP/2 lanes per edge, one uint (2 bf16 cols) per lane.
// msg row per edge = CP*2 bytes (128B for CP=64, 64B for CP=32), full-line.
template <int CP>
__global__ __launch_bounds__(256, 8) void edge_scatter(
    const ushort* __restrict__ Tlb, const int* __restrict__ srcs,
    const int2* __restrict__ pw, ushort* __restrict__ msg, int cp0) {
  constexpr int L = CP / 2;
  int gid = blockIdx.x * 256 + threadIdx.x;
  int e = gid / L;
  int cp = gid % L;
  if (e >= EE) return;
  int s = srcs[e];
  int2 p = pw[e];
  float w = __int_as_float(p.y);
  int gcp = cp0 + cp;                     // global col-pair index (0..63)
  int chunk = gcp >> 4, coff = gcp & 15;  // tlb chunk = 32 cols = 16 uints
  const uint* cb = (const uint*)Tlb;
  uint t = cb[(size_t)chunk * NN * 16 + (size_t)s * 16 + coff];
  float f0 = w * bflo(t);
  float f1 = w * bfhi(t);
  uint m = ((uint)f2bf(f1) << 16) | (uint)f2bf(f0);
  ((uint*)msg)[(size_t)p.x * L + cp] = m;
}

// ---------- big path pass 2: contiguous segmented reduce + combine ----------
template <int CP, bool STATS>
__global__ __launch_bounds__(256, 8) void seg_reduce(
    const ushort* __restrict__ msg, const float* __restrict__ Tr,
    const int* __restrict__ rs, const float* __restrict__ invd,
    const float* __restrict__ bias, float* __restrict__ out,
    float* __restrict__ stats, int c0, int F) {
  constexpr int L = CP / 2;
  const int tid = threadIdx.x;
  const int cp = tid % L;
  const int n = blockIdx.x * (256 / L) + tid / L;  // grid exact, n < NN
  const uint* M = (const uint*)msg;
  const int r0 = rs[n], r1 = rs[n + 1];
  float2 acc = {0.f, 0.f};
  int j = r0;
  for (; j + 4 <= r1; j += 4) {
    uint t0 = M[(size_t)(j + 0) * L + cp];
    uint t1 = M[(size_t)(j + 1) * L + cp];
    uint t2 = M[(size_t)(j + 2) * L + cp];
    uint t3 = M[(size_t)(j + 3) * L + cp];
    acc.x += (bflo(t0) + bflo(t1)) + (bflo(t2) + bflo(t3));
    acc.y += (bfhi(t0) + bfhi(t1)) + (bfhi(t2) + bfhi(t3));
  }
  for (; j < r1; ++j) {
    uint t = M[(size_t)j * L + cp];
    acc.x += bflo(t);
    acc.y += bfhi(t);
  }
  const int c = c0 + 2 * cp;
  const float iv = invd[n];
  float2 tr = *(const float2*)(Tr + (size_t)n * F + c);
  float2 v;
  v.x = fmaf(acc.x, iv, tr.x + bias[c]);
  v.y = fmaf(acc.y, iv, tr.y + bias[c + 1]);
  *(float2*)(out + (size_t)n * F + c) = v;
  if constexpr (STATS) {
    float2 s = v, q = {v.x * v.x, v.y * v.y};
    if constexpr (L == 16) {
      s.x += __shfl_xor(s.x, 16, 64); s.y += __shfl_xor(s.y, 16, 64);
      q.x += __shfl_xor(q.x, 16, 64); q.y += __shfl_xor(q.y, 16, 64);
    }
    s.x += __shfl_xor(s.x, 32, 64); s.y += __shfl_xor(s.y, 32, 64);
    q.x += __shfl_xor(q.x, 32, 64); q.y += __shfl_xor(q.y, 32, 64);
    __shared__ float2 rS[4][L];
    __shared__ float2 rQ[4][L];
    const int wid = tid >> 6, wl = tid & 63;
    if (wl < L) { rS[wid][wl] = s; rQ[wid][wl] = q; }
    __syncthreads();
    if (tid < L) {
      float2 S = rS[0][tid], Q = rQ[0][tid];
#pragma unroll
      for (int w2 = 1; w2 < 4; ++w2) {
        S.x += rS[w2][tid].x; S.y += rS[w2][tid].y;
        Q.x += rQ[w2][tid].x; Q.y += rQ[w2][tid].y;
      }
      int col = c0 + 2 * tid;
      atomicAdd(&stats[col], S.x);
      atomicAdd(&stats[col + 1], S.y);
      atomicAdd(&stats[128 + col], Q.x);
      atomicAdd(&stats[128 + col + 1], Q.y);
    }
  }
}

// ---------- fallback: R6 chunked gather (proven 1138 us) ----------
template <int F, bool STATS>
__global__ __launch_bounds__(256, 4) void gather_chunk(
    const ushort* __restrict__ Tlb, const float* __restrict__ Tr,
    const int* __restrict__ rs, const int2* __restrict__ esw,
    const float* __restrict__ invd, const float* __restrict__ bias,
    float* __restrict__ out, float* __restrict__ stats, int chunk) {
  constexpr int ECAP = 512;
  const int tid = threadIdx.x;
  const ushort* cbase = Tlb + (size_t)chunk * NN * 32;
  __shared__ int2 eL[ECAP];
  __shared__ float sink;
  if (tid == 0) sink = 0.f;
  {
    const int total4 = NN * 64 / 16;
    const float4* cb4 = (const float4*)cbase;
    int nsl = gridDim.x >> 3;
    int sl = blockIdx.x >> 3;
    if (sl < nsl) {
      int per = (total4 + nsl - 1) / nsl;
      int i0 = sl * per;
      int i1 = min(i0 + per, total4);
      float acc = 0.f;
      for (int i = i0 + tid; i < i1; i += 256) {
        float4 t = cb4[i];
        acc += t.x + t.y + t.z + t.w;
      }
      atomicAdd(&sink, acc);
    }
  }
  const int nb0 = blockIdx.x * 16;
  const int e0 = rs[nb0];
  const int e1 = rs[nb0 + 16];
  const int ecnt = min(e1 - e0, ECAP);
  for (int i = tid; i < ecnt; i += 256) eL[i] = esw[e0 + i];
  __syncthreads();
  const uint* cb = (const uint*)cbase;
  const int l = tid & 15;
  const int n = nb0 + (tid >> 4);
  const int r0 = rs[n], r1 = rs[n + 1];
  float2 acc = {0.f, 0.f};
  for (int j0 = r0; j0 < r1; j0 += 8) {
    int sidx[8];
    float ww[8];
#pragma unroll
    for (int u = 0; u < 8; ++u) {
      int jj = (j0 + u < r1) ? (j0 + u) : r0;
      int li = jj - e0;
      int2 p = (li < ecnt) ? eL[li] : esw[jj];
      sidx[u] = p.x;
      ww[u] = (j0 + u < r1) ? __int_as_float(p.y) : 0.f;
    }
    uint t[8];
#pragma unroll
    for (int u = 0; u < 8; ++u) t[u] = cb[(size_t)sidx[u] * 16 + l];
#pragma unroll
    for (int u = 0; u < 8; ++u) {
      acc.x = fmaf(ww[u], bflo(t[u]), acc.x);
      acc.y = fmaf(ww[u], bfhi(t[u]), acc.y);
    }
  }
  const int c0 = chunk * 32 + 2 * l;
  const float iv = invd[n];
  float2 tr = *(const float2*)(Tr + (size_t)n * F + c0);
  float2 v;
  v.x = fmaf(acc.x, iv, tr.x + bias[c0]);
  v.y = fmaf(acc.y, iv, tr.y + bias[c0 + 1]);
  float* op = out + (size_t)n * F + c0;
  __builtin_nontemporal_store(v.x, op);
  __builtin_nontemporal_store(v.y, op + 1);
  if constexpr (STATS) {
    float2 s = v;
    float2 q = {v.x * v.x, v.y * v.y};
    s.x += __shfl_xor(s.x, 16, 64); s.y += __shfl_xor(s.y, 16, 64);
    q.x += __shfl_xor(q.x, 16, 64); q.y += __shfl_xor(q.y, 16, 64);
    s.x += __shfl_xor(s.x, 32, 64); s.y += __shfl_xor(s.y, 32, 64);
    q.x += __shfl_xor(q.x, 32, 64); q.y += __shfl_xor(q.y, 32, 64);
    __shared__ float2 rS[4][16];
    __shared__ float2 rQ[4][16];
    const int wid = tid >> 6, wl = tid & 63;
    if (wl < 16) { rS[wid][wl] = s; rQ[wid][wl] = q; }
    __syncthreads();
    if (tid < 16) {
      float2 S = rS[0][tid], Q = rQ[0][tid];
#pragma unroll
      for (int w2 = 1; w2 < 4; ++w2) {
        S.x += rS[w2][tid].x; S.y += rS[w2][tid].y;
        Q.x += rQ[w2][tid].x; Q.y += rQ[w2][tid].y;
      }
      int col = chunk * 32 + 2 * tid;
      atomicAdd(&stats[col], S.x);
      atomicAdd(&stats[col + 1], S.y);
      atomicAdd(&stats[128 + col], Q.x);
      atomicAdd(&stats[128 + col + 1], Q.y);
    }
  }
}

// ---------- BN finalize ----------
__global__ void bn_fin(const float* __restrict__ stats, const float* __restrict__ gamma,
                       const float* __restrict__ beta, float* __restrict__ ss) {
  int f = threadIdx.x;
  float mu = stats[f] * (1.0f / (float)NN);
  float ex2 = stats[128 + f] * (1.0f / (float)NN);
  float var = ex2 - mu * mu;
  float sc = gamma[f] * rsqrtf(var + 1e-5f);
  ss[f] = sc;
  ss[128 + f] = beta[f] - mu * sc;
}

extern "C" void kernel_launch(void* const* d_in, const int* in_sizes, int n_in,
                              void* d_out, int out_size, void* d_ws, size_t ws_size,
                              hipStream_t stream) {
  (void)in_sizes; (void)n_in; (void)out_size;
  const float* x   = (const float*)d_in[0];
  const int*   ei  = (const int*)d_in[1];
  const float* ew  = (const float*)d_in[2];
  const float* Wl0 = (const float*)d_in[3];
  const float* Wr0 = (const float*)d_in[4];
  const float* b0  = (const float*)d_in[5];
  const float* Wl1 = (const float*)d_in[6];
  const float* Wr1 = (const float*)d_in[7];
  const float* b1  = (const float*)d_in[8];
  const float* Wl2 = (const float*)d_in[9];
  const float* Wr2 = (const float*)d_in[10];
  const float* b2  = (const float*)d_in[11];
  const float* g0  = (const float*)d_in[12];
  const float* be0 = (const float*)d_in[13];
  const float* g1  = (const float*)d_in[14];
  const float* be1 = (const float*)d_in[15];
  float* out = (float*)d_out;

  size_t off = 0;
  auto alloc = [&](size_t b) -> void* {
    void* p = (char*)d_ws + off;
    off += (b + 255) & ~(size_t)255;
    return p;
  };
  ushort* tlb  = (ushort*)alloc((size_t)NN * 128 * 2);  // 12.8 MB
  float* tr    = (float*)alloc((size_t)NN * 128 * 4);   // 25.6 MB
  float* hpre  = (float*)alloc((size_t)NN * 128 * 4);   // 25.6 MB
  // overlay region: big path {srcs 2.4MB, pw 4.8MB} / fallback {esw 4.8MB}
  char*  greg  = (char*)alloc((size_t)EE * 12);         // 7.2 MB
  int*   srcs  = (int*)greg;
  int2*  pw    = (int2*)(greg + ((size_t)EE * 4 + 255 & ~(size_t)255));
  int2*  esw   = (int2*)greg;
  int*   rs    = (int*)alloc((size_t)(NN + 1) * 4);
  int*   cs    = (int*)alloc((size_t)(NN + 1) * 4);
  int*   cur_d = (int*)alloc((size_t)NN * 4);
  int*   cur_s = (int*)alloc((size_t)NN * 4);
  float* invd  = (float*)alloc((size_t)NN * 4);
  float* stats = (float*)alloc(256 * 4);
  float* ssb   = (float*)alloc(256 * 4);
  ushort* msg  = (ushort*)((char*)d_ws + off);          // remainder
  size_t msg_cap = (ws_size > off) ? ws_size - off : 0;
  // mode: 2 = 64-col passes (msg 76.8MB), 1 = 32-col (38.4MB), 0 = fallback
  const int mode = (msg_cap >= (size_t)EE * 64 * 2) ? 2
                 : (msg_cap >= (size_t)EE * 32 * 2) ? 1 : 0;

  const int EB = (EE + 255) / 256;

  // ---- prep
  hipMemsetAsync(cur_s, 0, (size_t)NN * 4, stream);
  hipMemsetAsync(cur_d, 0, (size_t)NN * 4, stream);
  count2_k<<<EB, 256, 0, stream>>>(ei, cur_s, cur_d);
  scan_k<<<1, 1024, 0, stream>>>(cur_d, rs);
  invd_k<<<(NN + 255) / 256, 256, 0, stream>>>(rs, invd);
  if (mode) {
    scan_k<<<1, 1024, 0, stream>>>(cur_s, cs);
    hipMemcpyAsync(cur_s, cs, (size_t)NN * 4, hipMemcpyDeviceToDevice, stream);
    hipMemcpyAsync(cur_d, rs, (size_t)NN * 4, hipMemcpyDeviceToDevice, stream);
    fill2_k<<<EB, 256, 0, stream>>>(ei, ew, cur_s, cur_d, srcs, pw);
  } else {
    hipMemcpyAsync(cur_d, rs, (size_t)NN * 4, hipMemcpyDeviceToDevice, stream);
    fill_k<<<EB, 256, 0, stream>>>(ei, ew, cur_d, esw);
  }

  // aggregation for one layer: dst = mean-agg + Tr + bias (+stats)
  auto agg = [&](int F, const float* bias, float* dst, bool st) {
    if (mode == 2) {
      for (int c0 = 0; c0 < F; c0 += 64) {
        edge_scatter<64><<<EE * 32 / 256, 256, 0, stream>>>(tlb, srcs, pw, msg, c0 / 2);
        if (st) seg_reduce<64, true><<<NN * 32 / 256, 256, 0, stream>>>(msg, tr, rs, invd, bias, dst, stats, c0, F);
        else    seg_reduce<64, false><<<NN * 32 / 256, 256, 0, stream>>>(msg, tr, rs, invd, bias, dst, stats, c0, F);
      }
    } else if (mode == 1) {
      for (int c0 = 0; c0 < F; c0 += 32) {
        edge_scatter<32><<<EE * 16 / 256, 256, 0, stream>>>(tlb, srcs, pw, msg, c0 / 2);
        if (st) seg_reduce<32, true><<<NN * 16 / 256, 256, 0, stream>>>(msg, tr, rs, invd, bias, dst, stats, c0, F);
        else    seg_reduce<32, false><<<NN * 16 / 256, 256, 0, stream>>>(msg, tr, rs, invd, bias, dst, stats, c0, F);
      }
    } else {
      const int GB = NN / 16;
      if (F == 128) {
        for (int c = 0; c < 4; ++c) {
          if (st) gather_chunk<128, true><<<GB, 256, 0, stream>>>(tlb, tr, rs, esw, invd, bias, dst, stats, c);
          else    gather_chunk<128, false><<<GB, 256, 0, stream>>>(tlb, tr, rs, esw, invd, bias, dst, stats, c);
        }
      } else {
        for (int c = 0; c < 2; ++c)
          gather_chunk<64, false><<<GB, 256, 0, stream>>>(tlb, tr, rs, esw, invd, bias, dst, stats, c);
      }
    }
  };

  // ---- layer 0
  gemm_dual<128><<<(NN + 63) / 64, 256, 0, stream>>>(x, Wl0, Wr0, nullptr, tlb, tr);
  hipMemsetAsync(stats, 0, 256 * 4, stream);
  agg(128, b0, hpre, true);
  bn_fin<<<1, 128, 0, stream>>>(stats, g0, be0, ssb);

  // ---- layer 1
  gemm_dual<128><<<(NN + 63) / 64, 256, 0, stream>>>(hpre, Wl1, Wr1, ssb, tlb, tr);
  hipMemsetAsync(stats, 0, 256 * 4, stream);
  agg(128, b1, hpre, true);
  bn_fin<<<1, 128, 0, stream>>>(stats, g1, be1, ssb);

  // ---- layer 2
  gemm_dual<64><<<(NN + 127) / 128, 256, 0, stream>>>(hpre, Wl2, Wr2, ssb, tlb, tr);
  agg(64, b2, out, false);
}

// Round 8
// 967.273 us; speedup vs baseline: 2.0618x; 2.0618x over previous
//
#include <hip/hip_runtime.h>
#include <hip/hip_bf16.h>

#define NN 50000
#define EE 600000

#if __has_builtin(__builtin_amdgcn_global_atomic_fadd_v2bf16)
#define USE_PK 1
typedef short bf2v __attribute__((ext_vector_type(2)));
#else
#define USE_PK 0
#endif

__device__ inline void fma4(float4& a, float s, const float4 w) {
  a.x = fmaf(s, w.x, a.x);
  a.y = fmaf(s, w.y, a.y);
  a.z = fmaf(s, w.z, a.z);
  a.w = fmaf(s, w.w, a.w);
}

__device__ inline ushort f2bf(float x) {  // round-to-nearest-even bf16
  unsigned u = __float_as_uint(x);
  u = (u + 0x7fffu + ((u >> 16) & 1u)) >> 16;
  return (ushort)u;
}
__device__ inline float bflo(uint t) { return __uint_as_float(t << 16); }
__device__ inline float bfhi(uint t) { return __uint_as_float(t & 0xffff0000u); }

// ---------- graph preprocessing ----------
__global__ void count2_k(const int* __restrict__ ei, int* __restrict__ cnt_s,
                         int* __restrict__ cnt_d) {
  int e = blockIdx.x * 256 + threadIdx.x;
  if (e < EE) {
    atomicAdd(&cnt_s[ei[e]], 1);
    atomicAdd(&cnt_d[ei[EE + e]], 1);
  }
}

__global__ void scan_k(const int* __restrict__ cnt, int* __restrict__ rs) {
  __shared__ int ls[1024];
  const int t = threadIdx.x;
  const int STRIP = (NN + 1023) >> 10;  // 49
  int i0 = t * STRIP;
  int i1 = min(i0 + STRIP, NN);
  int s = 0;
  for (int i = i0; i < i1; ++i) s += cnt[i];
  ls[t] = s;
  __syncthreads();
  for (int off = 1; off < 1024; off <<= 1) {
    int v = (t >= off) ? ls[t - off] : 0;
    __syncthreads();
    ls[t] += v;
    __syncthreads();
  }
  int run = (t == 0) ? 0 : ls[t - 1];
  for (int i = i0; i < i1; ++i) { rs[i] = run; run += cnt[i]; }
  if (t == 0) rs[NN] = EE;
}

// CSC order (grouped by src): srcs[p] = src, dw[p] = {dst, w}
__global__ void fill_csc_k(const int* __restrict__ ei, const float* __restrict__ ew,
                           int* __restrict__ cur_s, int* __restrict__ srcs,
                           int2* __restrict__ dw) {
  int e = blockIdx.x * 256 + threadIdx.x;
  if (e < EE) {
    int s = ei[e], d = ei[EE + e];
    int pc = atomicAdd(&cur_s[s], 1);
    srcs[pc] = s;
    int2 v;
    v.x = d;
    v.y = __float_as_int(ew[e]);
    dw[pc] = v;
  }
}

__global__ void invd_k(const int* __restrict__ rs, float* __restrict__ invd) {
  int n = blockIdx.x * 256 + threadIdx.x;
  if (n < NN) {
    int d = rs[n + 1] - rs[n];
    invd[n] = 1.0f / (float)max(d, 1);
  }
}

// ---------- fused dual GEMM: Tl(bf16,col-chunked) / Tr(f32) ----------
// Tl layout: chunk c (32 cols) at Tlb + c*NN*32 ushorts.
template <int F>
__global__ __launch_bounds__(256, 3) void gemm_dual(
    const float* __restrict__ H, const float* __restrict__ Wl,
    const float* __restrict__ Wr, const float* __restrict__ ss,
    ushort* __restrict__ Tlb, float* __restrict__ Tr) {
  constexpr int K = 128;
  constexpr int Kc = 32;
  constexpr int TX = F / 4;
  constexpr int TY = 256 / TX;
  constexpr int ROWS = TY * 8;
  constexpr int HS = ROWS + 4;
  __shared__ __align__(16) float Wls[Kc][F];
  __shared__ __align__(16) float Wrs[Kc][F];
  __shared__ __align__(16) float Hs[Kc][HS];
  const int tid = threadIdx.x;
  const int tx = tid % TX, ty = tid / TX;
  const int n0 = blockIdx.x * ROWS;

  const float4 z4 = {0.f, 0.f, 0.f, 0.f};
  float4 aAA[4], aAB[4], aBA[4], aBB[4];
#pragma unroll
  for (int r = 0; r < 4; ++r) { aAA[r] = z4; aAB[r] = z4; aBA[r] = z4; aBB[r] = z4; }

  for (int kc = 0; kc < K; kc += Kc) {
    __syncthreads();
    for (int idx = tid; idx < Kc * (F / 4); idx += 256) {
      int k = idx / (F / 4), c = idx % (F / 4);
      ((float4*)(&Wls[k][0]))[c] = ((const float4*)Wl)[(kc + k) * (F / 4) + c];
      ((float4*)(&Wrs[k][0]))[c] = ((const float4*)Wr)[(kc + k) * (F / 4) + c];
    }
    for (int idx = tid; idx < ROWS * 8; idx += 256) {
      int i = idx >> 3, k4 = idx & 7;
      int nrow = n0 + i;
      float4 hv = z4;
      if (nrow < NN) hv = ((const float4*)H)[nrow * 32 + (kc >> 2) + k4];
      if (ss) {
        int gk = kc + k4 * 4;
        hv.x = fmaxf(fmaf(hv.x, ss[gk + 0], ss[128 + gk + 0]), 0.f);
        hv.y = fmaxf(fmaf(hv.y, ss[gk + 1], ss[128 + gk + 1]), 0.f);
        hv.z = fmaxf(fmaf(hv.z, ss[gk + 2], ss[128 + gk + 2]), 0.f);
        hv.w = fmaxf(fmaf(hv.w, ss[gk + 3], ss[128 + gk + 3]), 0.f);
      }
      Hs[k4 * 4 + 0][i] = hv.x;
      Hs[k4 * 4 + 1][i] = hv.y;
      Hs[k4 * 4 + 2][i] = hv.z;
      Hs[k4 * 4 + 3][i] = hv.w;
    }
    __syncthreads();
#pragma unroll 4
    for (int k = 0; k < Kc; ++k) {
      float4 wA = *(const float4*)&Wls[k][tx * 4];
      float4 wB = *(const float4*)&Wrs[k][tx * 4];
      float4 hA = *(const float4*)&Hs[k][ty * 4];
      float4 hB = *(const float4*)&Hs[k][ROWS / 2 + ty * 4];
      fma4(aAA[0], hA.x, wA); fma4(aAA[1], hA.y, wA); fma4(aAA[2], hA.z, wA); fma4(aAA[3], hA.w, wA);
      fma4(aAB[0], hA.x, wB); fma4(aAB[1], hA.y, wB); fma4(aAB[2], hA.z, wB); fma4(aAB[3], hA.w, wB);
      fma4(aBA[0], hB.x, wA); fma4(aBA[1], hB.y, wA); fma4(aBA[2], hB.z, wA); fma4(aBA[3], hB.w, wA);
      fma4(aBB[0], hB.x, wB); fma4(aBB[1], hB.y, wB); fma4(aBB[2], hB.z, wB); fma4(aBB[3], hB.w, wB);
    }
  }
  float4* Tr4 = (float4*)Tr;
  const int c0 = tx * 4;
  const int chunk = c0 >> 5;
  const int coff = c0 & 31;
#pragma unroll
  for (int r = 0; r < 4; ++r) {
    int nA = n0 + ty * 4 + r;
    if (nA < NN) {
      ushort4 u4 = {f2bf(aAA[r].x), f2bf(aAA[r].y), f2bf(aAA[r].z), f2bf(aAA[r].w)};
      *(ushort4*)(Tlb + (size_t)chunk * NN * 32 + (size_t)nA * 32 + coff) = u4;
      Tr4[(size_t)nA * TX + tx] = aAB[r];
    }
    int nB = n0 + ROWS / 2 + ty * 4 + r;
    if (nB < NN) {
      ushort4 u4 = {f2bf(aBA[r].x), f2bf(aBA[r].y), f2bf(aBA[r].z), f2bf(aBA[r].w)};
      *(ushort4*)(Tlb + (size_t)chunk * NN * 32 + (size_t)nB * 32 + coff) = u4;
      Tr4[(size_t)nB * TX + tx] = aBB[r];
    }
  }
}

// ---------- edge-parallel aggregation via HW atomics ----------
// CSC-ordered edges: Tl reads are L1/L2-hot streaming (proven fast in R7);
// scattered side is fire-and-forget pk_add_bf16 atomics (write-class path).
template <int F>
__global__ __launch_bounds__(256, 8) void edge_atomic(
    const ushort* __restrict__ Tlb, const int* __restrict__ srcs,
    const int2* __restrict__ dw, void* __restrict__ agg) {
  constexpr int L = F / 2;
  int gid = blockIdx.x * 256 + threadIdx.x;
  int e = gid / L;
  int cp = gid % L;
  if (e >= EE) return;
  int s = srcs[e];
  int2 p = dw[e];
  float w = __int_as_float(p.y);
  int chunk = cp >> 4, coff = cp & 15;
  uint t = ((const uint*)Tlb)[(size_t)chunk * NN * 16 + (size_t)s * 16 + coff];
  float f0 = w * bflo(t);
  float f1 = w * bfhi(t);
#if USE_PK
  bf2v v;
  v.x = (short)f2bf(f0);
  v.y = (short)f2bf(f1);
  __builtin_amdgcn_global_atomic_fadd_v2bf16((bf2v*)((char*)agg + ((size_t)p.x * L + cp) * 4), v);
#else
  float* a = (float*)agg + ((size_t)p.x * L + cp) * 2;
  atomicAdd(a, f0);
  atomicAdd(a + 1, f1);
#endif
}

// ---------- combine: out = agg*invd + Tr + bias (+BN stats) ----------
// 40 nodes per block; per-thread column fixed across node iterations so BN
// stats accumulate in registers, one LDS+global reduce per block.
template <int F, bool STATS>
__global__ __launch_bounds__(256, 8) void combine(
    const void* __restrict__ agg, const float* __restrict__ Tr,
    const float* __restrict__ invd, const float* __restrict__ bias,
    float* __restrict__ out, float* __restrict__ stats) {
  constexpr int L = F / 2;        // 64 or 32 col-pairs
  constexpr int NPI = 256 / L;    // nodes per iteration: 4 or 8
  constexpr int NPB = 40;         // 50000 / 40 = 1250 blocks exact
  const int tid = threadIdx.x;
  const int cp = tid % L;
  const int c = 2 * cp;
  const int nl = tid / L;
  const int n0 = blockIdx.x * NPB;
  const float bx = bias[c], by = bias[c + 1];
  float2 S = {0.f, 0.f}, Q = {0.f, 0.f};
#pragma unroll
  for (int it = 0; it < NPB / NPI; ++it) {
    int n = n0 + it * NPI + nl;
    float a0, a1;
#if USE_PK
    uint t = ((const uint*)agg)[(size_t)n * L + cp];
    a0 = bflo(t);
    a1 = bfhi(t);
#else
    float2 af = ((const float2*)agg)[(size_t)n * L + cp];
    a0 = af.x;
    a1 = af.y;
#endif
    float iv = invd[n];
    float2 tr = *(const float2*)(Tr + (size_t)n * F + c);
    float2 v;
    v.x = fmaf(a0, iv, tr.x + bx);
    v.y = fmaf(a1, iv, tr.y + by);
    *(float2*)(out + (size_t)n * F + c) = v;
    if constexpr (STATS) {
      S.x += v.x; S.y += v.y;
      Q.x += v.x * v.x; Q.y += v.y * v.y;
    }
  }
  if constexpr (STATS) {
    __shared__ float2 sS[256 / 64][L];
    __shared__ float2 sQ[256 / 64][L];
    const int wid = tid >> 6, wl = tid & 63;
    if constexpr (L == 64) {
      sS[wid][wl] = S;
      sQ[wid][wl] = Q;
    } else {
      // L==32: two nodes per wave share cp via lanes l and l+32 — fold first
      S.x += __shfl_xor(S.x, 32, 64); S.y += __shfl_xor(S.y, 32, 64);
      Q.x += __shfl_xor(Q.x, 32, 64); Q.y += __shfl_xor(Q.y, 32, 64);
      if (wl < 32) { sS[wid][wl] = S; sQ[wid][wl] = Q; }
    }
    __syncthreads();
    if (tid < L) {
      float2 Sa = sS[0][tid], Qa = sQ[0][tid];
#pragma unroll
      for (int w2 = 1; w2 < 4; ++w2) {
        Sa.x += sS[w2][tid].x; Sa.y += sS[w2][tid].y;
        Qa.x += sQ[w2][tid].x; Qa.y += sQ[w2][tid].y;
      }
      int col = 2 * tid;
      atomicAdd(&stats[col], Sa.x);
      atomicAdd(&stats[col + 1], Sa.y);
      atomicAdd(&stats[128 + col], Qa.x);
      atomicAdd(&stats[128 + col + 1], Qa.y);
    }
  }
}

// ---------- BN finalize ----------
__global__ void bn_fin(const float* __restrict__ stats, const float* __restrict__ gamma,
                       const float* __restrict__ beta, float* __restrict__ ss) {
  int f = threadIdx.x;
  float mu = stats[f] * (1.0f / (float)NN);
  float ex2 = stats[128 + f] * (1.0f / (float)NN);
  float var = ex2 - mu * mu;
  float sc = gamma[f] * rsqrtf(var + 1e-5f);
  ss[f] = sc;
  ss[128 + f] = beta[f] - mu * sc;
}

extern "C" void kernel_launch(void* const* d_in, const int* in_sizes, int n_in,
                              void* d_out, int out_size, void* d_ws, size_t ws_size,
                              hipStream_t stream) {
  (void)in_sizes; (void)n_in; (void)out_size; (void)ws_size;
  const float* x   = (const float*)d_in[0];
  const int*   ei  = (const int*)d_in[1];
  const float* ew  = (const float*)d_in[2];
  const float* Wl0 = (const float*)d_in[3];
  const float* Wr0 = (const float*)d_in[4];
  const float* b0  = (const float*)d_in[5];
  const float* Wl1 = (const float*)d_in[6];
  const float* Wr1 = (const float*)d_in[7];
  const float* b1  = (const float*)d_in[8];
  const float* Wl2 = (const float*)d_in[9];
  const float* Wr2 = (const float*)d_in[10];
  const float* b2  = (const float*)d_in[11];
  const float* g0  = (const float*)d_in[12];
  const float* be0 = (const float*)d_in[13];
  const float* g1  = (const float*)d_in[14];
  const float* be1 = (const float*)d_in[15];
  float* out = (float*)d_out;

  size_t off = 0;
  auto alloc = [&](size_t b) -> void* {
    void* p = (char*)d_ws + off;
    off += (b + 255) & ~(size_t)255;
    return p;
  };
  ushort* tlb  = (ushort*)alloc((size_t)NN * 128 * 2);  // 12.8 MB
  float* tr    = (float*)alloc((size_t)NN * 128 * 4);   // 25.6 MB
  float* hpre  = (float*)alloc((size_t)NN * 128 * 4);   // 25.6 MB
#if USE_PK
  const size_t AGG_B = (size_t)NN * 128 * 2;            // bf16 agg, 12.8 MB
#else
  const size_t AGG_B = (size_t)NN * 128 * 4;            // f32 agg, 25.6 MB
#endif
  void* agg    = alloc((size_t)NN * 128 * 4);
  int*  srcs   = (int*)alloc((size_t)EE * 4);           // 2.4 MB
  int2* dw     = (int2*)alloc((size_t)EE * 8);          // 4.8 MB
  int*  rs     = (int*)alloc((size_t)(NN + 1) * 4);
  int*  cur_s  = (int*)alloc((size_t)NN * 4);
  int*  cur_d  = (int*)alloc((size_t)NN * 4);
  int*  cs     = (int*)alloc((size_t)(NN + 1) * 4);
  float* invd  = (float*)alloc((size_t)NN * 4);
  float* stats = (float*)alloc(256 * 4);
  float* ssb   = (float*)alloc(256 * 4);
  // total ~98 MB (R7 proved >=150 MB available)

  const int EB = (EE + 255) / 256;

  // ---- prep: dst-degree (for invd), CSC fill
  hipMemsetAsync(cur_s, 0, (size_t)NN * 4, stream);
  hipMemsetAsync(cur_d, 0, (size_t)NN * 4, stream);
  count2_k<<<EB, 256, 0, stream>>>(ei, cur_s, cur_d);
  scan_k<<<1, 1024, 0, stream>>>(cur_d, rs);
  invd_k<<<(NN + 255) / 256, 256, 0, stream>>>(rs, invd);
  scan_k<<<1, 1024, 0, stream>>>(cur_s, cs);
  hipMemcpyAsync(cur_s, cs, (size_t)NN * 4, hipMemcpyDeviceToDevice, stream);
  fill_csc_k<<<EB, 256, 0, stream>>>(ei, ew, cur_s, srcs, dw);

  const int EG128 = (int)(((size_t)EE * 64 + 255) / 256);
  const int EG64  = (int)(((size_t)EE * 32 + 255) / 256);

  // ---- layer 0
  gemm_dual<128><<<(NN + 63) / 64, 256, 0, stream>>>(x, Wl0, Wr0, nullptr, tlb, tr);
  hipMemsetAsync(agg, 0, AGG_B, stream);
  hipMemsetAsync(stats, 0, 256 * 4, stream);
  edge_atomic<128><<<EG128, 256, 0, stream>>>(tlb, srcs, dw, agg);
  combine<128, true><<<NN / 40, 256, 0, stream>>>(agg, tr, invd, b0, hpre, stats);
  bn_fin<<<1, 128, 0, stream>>>(stats, g0, be0, ssb);

  // ---- layer 1 (BN0+ReLU folded into GEMM staging)
  gemm_dual<128><<<(NN + 63) / 64, 256, 0, stream>>>(hpre, Wl1, Wr1, ssb, tlb, tr);
  hipMemsetAsync(agg, 0, AGG_B, stream);
  hipMemsetAsync(stats, 0, 256 * 4, stream);
  edge_atomic<128><<<EG128, 256, 0, stream>>>(tlb, srcs, dw, agg);
  combine<128, true><<<NN / 40, 256, 0, stream>>>(agg, tr, invd, b1, hpre, stats);
  bn_fin<<<1, 128, 0, stream>>>(stats, g1, be1, ssb);

  // ---- layer 2 (BN1+ReLU folded; F=64 straight to d_out)
  gemm_dual<64><<<(NN + 127) / 128, 256, 0, stream>>>(hpre, Wl2, Wr2, ssb, tlb, tr);
  hipMemsetAsync(agg, 0, AGG_B / 2, stream);
  edge_atomic<64><<<EG64, 256, 0, stream>>>(tlb, srcs, dw, agg);
  combine<64, false><<<NN / 40, 256, 0, stream>>>(agg, tr, invd, b2, out, nullptr);
}

// Round 9
// 865.617 us; speedup vs baseline: 2.3039x; 1.1174x over previous
//
#include <hip/hip_runtime.h>
#include <hip/hip_bf16.h>

#define NN 50000
#define EE 600000
#define SREP 64   // stats replicas (atomic decontention)

#if __has_builtin(__builtin_amdgcn_global_atomic_fadd_v2bf16)
#define USE_PK 1
typedef short bf2v __attribute__((ext_vector_type(2)));
#else
#define USE_PK 0
#endif

__device__ inline void fma4(float4& a, float s, const float4 w) {
  a.x = fmaf(s, w.x, a.x);
  a.y = fmaf(s, w.y, a.y);
  a.z = fmaf(s, w.z, a.z);
  a.w = fmaf(s, w.w, a.w);
}

__device__ inline ushort f2bf(float x) {  // round-to-nearest-even bf16
  unsigned u = __float_as_uint(x);
  u = (u + 0x7fffu + ((u >> 16) & 1u)) >> 16;
  return (ushort)u;
}
__device__ inline float bflo(uint t) { return __uint_as_float(t << 16); }
__device__ inline float bfhi(uint t) { return __uint_as_float(t & 0xffff0000u); }

// ---------- graph preprocessing ----------
__global__ void count2_k(const int* __restrict__ ei, int* __restrict__ cnt_s,
                         int* __restrict__ cnt_d) {
  int e = blockIdx.x * 256 + threadIdx.x;
  if (e < EE) {
    atomicAdd(&cnt_s[ei[e]], 1);
    atomicAdd(&cnt_d[ei[EE + e]], 1);
  }
}

__global__ void scan_k(const int* __restrict__ cnt, int* __restrict__ rs) {
  __shared__ int ls[1024];
  const int t = threadIdx.x;
  const int STRIP = (NN + 1023) >> 10;  // 49
  int i0 = t * STRIP;
  int i1 = min(i0 + STRIP, NN);
  int s = 0;
  for (int i = i0; i < i1; ++i) s += cnt[i];
  ls[t] = s;
  __syncthreads();
  for (int off = 1; off < 1024; off <<= 1) {
    int v = (t >= off) ? ls[t - off] : 0;
    __syncthreads();
    ls[t] += v;
    __syncthreads();
  }
  int run = (t == 0) ? 0 : ls[t - 1];
  for (int i = i0; i < i1; ++i) { rs[i] = run; run += cnt[i]; }
  if (t == 0) rs[NN] = EE;
}

// CSC order (grouped by src): srcs[p] = src, dw[p] = {dst, w}
__global__ void fill_csc_k(const int* __restrict__ ei, const float* __restrict__ ew,
                           int* __restrict__ cur_s, int* __restrict__ srcs,
                           int2* __restrict__ dw) {
  int e = blockIdx.x * 256 + threadIdx.x;
  if (e < EE) {
    int s = ei[e], d = ei[EE + e];
    int pc = atomicAdd(&cur_s[s], 1);
    srcs[pc] = s;
    int2 v;
    v.x = d;
    v.y = __float_as_int(ew[e]);
    dw[pc] = v;
  }
}

__global__ void invd_k(const int* __restrict__ rs, float* __restrict__ invd) {
  int n = blockIdx.x * 256 + threadIdx.x;
  if (n < NN) {
    int d = rs[n + 1] - rs[n];
    invd[n] = 1.0f / (float)max(d, 1);
  }
}

// ---------- fused dual GEMM: Tl(bf16,col-chunked) / Tr(f32) ----------
// Tl layout: chunk c (32 cols) at Tlb + c*NN*32 ushorts.
template <int F>
__global__ __launch_bounds__(256, 3) void gemm_dual(
    const float* __restrict__ H, const float* __restrict__ Wl,
    const float* __restrict__ Wr, const float* __restrict__ ss,
    ushort* __restrict__ Tlb, float* __restrict__ Tr) {
  constexpr int K = 128;
  constexpr int Kc = 32;
  constexpr int TX = F / 4;
  constexpr int TY = 256 / TX;
  constexpr int ROWS = TY * 8;
  constexpr int HS = ROWS + 4;
  __shared__ __align__(16) float Wls[Kc][F];
  __shared__ __align__(16) float Wrs[Kc][F];
  __shared__ __align__(16) float Hs[Kc][HS];
  const int tid = threadIdx.x;
  const int tx = tid % TX, ty = tid / TX;
  const int n0 = blockIdx.x * ROWS;

  const float4 z4 = {0.f, 0.f, 0.f, 0.f};
  float4 aAA[4], aAB[4], aBA[4], aBB[4];
#pragma unroll
  for (int r = 0; r < 4; ++r) { aAA[r] = z4; aAB[r] = z4; aBA[r] = z4; aBB[r] = z4; }

  for (int kc = 0; kc < K; kc += Kc) {
    __syncthreads();
    for (int idx = tid; idx < Kc * (F / 4); idx += 256) {
      int k = idx / (F / 4), c = idx % (F / 4);
      ((float4*)(&Wls[k][0]))[c] = ((const float4*)Wl)[(kc + k) * (F / 4) + c];
      ((float4*)(&Wrs[k][0]))[c] = ((const float4*)Wr)[(kc + k) * (F / 4) + c];
    }
    for (int idx = tid; idx < ROWS * 8; idx += 256) {
      int i = idx >> 3, k4 = idx & 7;
      int nrow = n0 + i;
      float4 hv = z4;
      if (nrow < NN) hv = ((const float4*)H)[nrow * 32 + (kc >> 2) + k4];
      if (ss) {
        int gk = kc + k4 * 4;
        hv.x = fmaxf(fmaf(hv.x, ss[gk + 0], ss[128 + gk + 0]), 0.f);
        hv.y = fmaxf(fmaf(hv.y, ss[gk + 1], ss[128 + gk + 1]), 0.f);
        hv.z = fmaxf(fmaf(hv.z, ss[gk + 2], ss[128 + gk + 2]), 0.f);
        hv.w = fmaxf(fmaf(hv.w, ss[gk + 3], ss[128 + gk + 3]), 0.f);
      }
      Hs[k4 * 4 + 0][i] = hv.x;
      Hs[k4 * 4 + 1][i] = hv.y;
      Hs[k4 * 4 + 2][i] = hv.z;
      Hs[k4 * 4 + 3][i] = hv.w;
    }
    __syncthreads();
#pragma unroll 4
    for (int k = 0; k < Kc; ++k) {
      float4 wA = *(const float4*)&Wls[k][tx * 4];
      float4 wB = *(const float4*)&Wrs[k][tx * 4];
      float4 hA = *(const float4*)&Hs[k][ty * 4];
      float4 hB = *(const float4*)&Hs[k][ROWS / 2 + ty * 4];
      fma4(aAA[0], hA.x, wA); fma4(aAA[1], hA.y, wA); fma4(aAA[2], hA.z, wA); fma4(aAA[3], hA.w, wA);
      fma4(aAB[0], hA.x, wB); fma4(aAB[1], hA.y, wB); fma4(aAB[2], hA.z, wB); fma4(aAB[3], hA.w, wB);
      fma4(aBA[0], hB.x, wA); fma4(aBA[1], hB.y, wA); fma4(aBA[2], hB.z, wA); fma4(aBA[3], hB.w, wA);
      fma4(aBB[0], hB.x, wB); fma4(aBB[1], hB.y, wB); fma4(aBB[2], hB.z, wB); fma4(aBB[3], hB.w, wB);
    }
  }
  float4* Tr4 = (float4*)Tr;
  const int c0 = tx * 4;
  const int chunk = c0 >> 5;
  const int coff = c0 & 31;
#pragma unroll
  for (int r = 0; r < 4; ++r) {
    int nA = n0 + ty * 4 + r;
    if (nA < NN) {
      ushort4 u4 = {f2bf(aAA[r].x), f2bf(aAA[r].y), f2bf(aAA[r].z), f2bf(aAA[r].w)};
      *(ushort4*)(Tlb + (size_t)chunk * NN * 32 + (size_t)nA * 32 + coff) = u4;
      Tr4[(size_t)nA * TX + tx] = aAB[r];
    }
    int nB = n0 + ROWS / 2 + ty * 4 + r;
    if (nB < NN) {
      ushort4 u4 = {f2bf(aBA[r].x), f2bf(aBA[r].y), f2bf(aBA[r].z), f2bf(aBA[r].w)};
      *(ushort4*)(Tlb + (size_t)chunk * NN * 32 + (size_t)nB * 32 + coff) = u4;
      Tr4[(size_t)nB * TX + tx] = aBB[r];
    }
  }
}

// ---------- edge-parallel aggregation via HW atomics ----------
// CSC-ordered edges: Tl reads are L1/L2-hot streaming; scattered side is
// fire-and-forget pk_add_bf16 atomics (write-class path, ~1.15 TB/s measured).
template <int F>
__global__ __launch_bounds__(256, 8) void edge_atomic(
    const ushort* __restrict__ Tlb, const int* __restrict__ srcs,
    const int2* __restrict__ dw, void* __restrict__ agg) {
  constexpr int L = F / 2;
  int gid = blockIdx.x * 256 + threadIdx.x;
  int e = gid / L;
  int cp = gid % L;
  if (e >= EE) return;
  int s = srcs[e];
  int2 p = dw[e];
  float w = __int_as_float(p.y);
  int chunk = cp >> 4, coff = cp & 15;
  uint t = ((const uint*)Tlb)[(size_t)chunk * NN * 16 + (size_t)s * 16 + coff];
  float f0 = w * bflo(t);
  float f1 = w * bfhi(t);
#if USE_PK
  bf2v v;
  v.x = (short)f2bf(f0);
  v.y = (short)f2bf(f1);
  __builtin_amdgcn_global_atomic_fadd_v2bf16((bf2v*)((char*)agg + ((size_t)p.x * L + cp) * 4), v);
#else
  float* a = (float*)agg + ((size_t)p.x * L + cp) * 2;
  atomicAdd(a, f0);
  atomicAdd(a + 1, f1);
#endif
}

// ---------- combine: out = agg*invd + Tr + bias (+BN stats) ----------
// Stats go to SREP replicated slots (blockIdx&63) — kills the same-address
// atomic serialization that made R8's combine 159us (1250-way -> ~20-way).
template <int F, bool STATS>
__global__ __launch_bounds__(256, 8) void combine(
    const void* __restrict__ agg, const float* __restrict__ Tr,
    const float* __restrict__ invd, const float* __restrict__ bias,
    float* __restrict__ out, float* __restrict__ statsb) {
  constexpr int L = F / 2;        // 64 or 32 col-pairs
  constexpr int NPI = 256 / L;    // nodes per iteration: 4 or 8
  constexpr int NPB = 40;         // 50000 / 40 = 1250 blocks exact
  const int tid = threadIdx.x;
  const int cp = tid % L;
  const int c = 2 * cp;
  const int nl = tid / L;
  const int n0 = blockIdx.x * NPB;
  const float bx = bias[c], by = bias[c + 1];
  float2 S = {0.f, 0.f}, Q = {0.f, 0.f};
#pragma unroll
  for (int it = 0; it < NPB / NPI; ++it) {
    int n = n0 + it * NPI + nl;
    float a0, a1;
#if USE_PK
    uint t = ((const uint*)agg)[(size_t)n * L + cp];
    a0 = bflo(t);
    a1 = bfhi(t);
#else
    float2 af = ((const float2*)agg)[(size_t)n * L + cp];
    a0 = af.x;
    a1 = af.y;
#endif
    float iv = invd[n];
    float2 tr = *(const float2*)(Tr + (size_t)n * F + c);
    float2 v;
    v.x = fmaf(a0, iv, tr.x + bx);
    v.y = fmaf(a1, iv, tr.y + by);
    *(float2*)(out + (size_t)n * F + c) = v;
    if constexpr (STATS) {
      S.x += v.x; S.y += v.y;
      Q.x += v.x * v.x; Q.y += v.y * v.y;
    }
  }
  if constexpr (STATS) {
    __shared__ float2 sS[256 / 64][L];
    __shared__ float2 sQ[256 / 64][L];
    const int wid = tid >> 6, wl = tid & 63;
    if constexpr (L == 64) {
      sS[wid][wl] = S;
      sQ[wid][wl] = Q;
    } else {
      S.x += __shfl_xor(S.x, 32, 64); S.y += __shfl_xor(S.y, 32, 64);
      Q.x += __shfl_xor(Q.x, 32, 64); Q.y += __shfl_xor(Q.y, 32, 64);
      if (wl < 32) { sS[wid][wl] = S; sQ[wid][wl] = Q; }
    }
    __syncthreads();
    if (tid < L) {
      float2 Sa = sS[0][tid], Qa = sQ[0][tid];
#pragma unroll
      for (int w2 = 1; w2 < 4; ++w2) {
        Sa.x += sS[w2][tid].x; Sa.y += sS[w2][tid].y;
        Qa.x += sQ[w2][tid].x; Qa.y += sQ[w2][tid].y;
      }
      float* sb = statsb + (size_t)(blockIdx.x & (SREP - 1)) * 256;
      int col = 2 * tid;
      atomicAdd(&sb[col], Sa.x);
      atomicAdd(&sb[col + 1], Sa.y);
      atomicAdd(&sb[128 + col], Qa.x);
      atomicAdd(&sb[128 + col + 1], Qa.y);
    }
  }
}

// ---------- BN finalize: reduce SREP replicas, compute scale/shift ----------
__global__ void bn_fin(const float* __restrict__ statsb, const float* __restrict__ gamma,
                       const float* __restrict__ beta, float* __restrict__ ss) {
  int f = threadIdx.x;
  float sum = 0.f, sq = 0.f;
#pragma unroll 8
  for (int r = 0; r < SREP; ++r) {
    sum += statsb[r * 256 + f];
    sq  += statsb[r * 256 + 128 + f];
  }
  float mu = sum * (1.0f / (float)NN);
  float ex2 = sq * (1.0f / (float)NN);
  float var = ex2 - mu * mu;
  float sc = gamma[f] * rsqrtf(var + 1e-5f);
  ss[f] = sc;
  ss[128 + f] = beta[f] - mu * sc;
}

extern "C" void kernel_launch(void* const* d_in, const int* in_sizes, int n_in,
                              void* d_out, int out_size, void* d_ws, size_t ws_size,
                              hipStream_t stream) {
  (void)in_sizes; (void)n_in; (void)out_size; (void)ws_size;
  const float* x   = (const float*)d_in[0];
  const int*   ei  = (const int*)d_in[1];
  const float* ew  = (const float*)d_in[2];
  const float* Wl0 = (const float*)d_in[3];
  const float* Wr0 = (const float*)d_in[4];
  const float* b0  = (const float*)d_in[5];
  const float* Wl1 = (const float*)d_in[6];
  const float* Wr1 = (const float*)d_in[7];
  const float* b1  = (const float*)d_in[8];
  const float* Wl2 = (const float*)d_in[9];
  const float* Wr2 = (const float*)d_in[10];
  const float* b2  = (const float*)d_in[11];
  const float* g0  = (const float*)d_in[12];
  const float* be0 = (const float*)d_in[13];
  const float* g1  = (const float*)d_in[14];
  const float* be1 = (const float*)d_in[15];
  float* out = (float*)d_out;

  size_t off = 0;
  auto alloc = [&](size_t b) -> void* {
    void* p = (char*)d_ws + off;
    off += (b + 255) & ~(size_t)255;
    return p;
  };
  ushort* tlb  = (ushort*)alloc((size_t)NN * 128 * 2);  // 12.8 MB
  float* tr    = (float*)alloc((size_t)NN * 128 * 4);   // 25.6 MB
  float* hpre  = (float*)alloc((size_t)NN * 128 * 4);   // 25.6 MB
#if USE_PK
  const size_t AGG_B = (size_t)NN * 128 * 2;            // bf16 agg
#else
  const size_t AGG_B = (size_t)NN * 128 * 4;            // f32 agg
#endif
  void* agg    = alloc((size_t)NN * 128 * 4);
  int*  srcs   = (int*)alloc((size_t)EE * 4);           // 2.4 MB
  int2* dw     = (int2*)alloc((size_t)EE * 8);          // 4.8 MB
  int*  rs     = (int*)alloc((size_t)(NN + 1) * 4);
  int*  cur_s  = (int*)alloc((size_t)NN * 4);
  int*  cur_d  = (int*)alloc((size_t)NN * 4);
  int*  cs     = (int*)alloc((size_t)(NN + 1) * 4);
  float* invd  = (float*)alloc((size_t)NN * 4);
  float* statsb = (float*)alloc((size_t)SREP * 256 * 4);  // 64 KB
  float* ssb   = (float*)alloc(256 * 4);
  // total ~98 MB (R7 proved >=150 MB available)

  const int EB = (EE + 255) / 256;

  // ---- prep: dst-degree (for invd), CSC fill
  hipMemsetAsync(cur_s, 0, (size_t)NN * 4, stream);
  hipMemsetAsync(cur_d, 0, (size_t)NN * 4, stream);
  count2_k<<<EB, 256, 0, stream>>>(ei, cur_s, cur_d);
  scan_k<<<1, 1024, 0, stream>>>(cur_d, rs);
  invd_k<<<(NN + 255) / 256, 256, 0, stream>>>(rs, invd);
  scan_k<<<1, 1024, 0, stream>>>(cur_s, cs);
  hipMemcpyAsync(cur_s, cs, (size_t)NN * 4, hipMemcpyDeviceToDevice, stream);
  fill_csc_k<<<EB, 256, 0, stream>>>(ei, ew, cur_s, srcs, dw);

  const int EG128 = (int)(((size_t)EE * 64 + 255) / 256);
  const int EG64  = (int)(((size_t)EE * 32 + 255) / 256);

  // ---- layer 0
  gemm_dual<128><<<(NN + 63) / 64, 256, 0, stream>>>(x, Wl0, Wr0, nullptr, tlb, tr);
  hipMemsetAsync(agg, 0, AGG_B, stream);
  hipMemsetAsync(statsb, 0, (size_t)SREP * 256 * 4, stream);
  edge_atomic<128><<<EG128, 256, 0, stream>>>(tlb, srcs, dw, agg);
  combine<128, true><<<NN / 40, 256, 0, stream>>>(agg, tr, invd, b0, hpre, statsb);
  bn_fin<<<1, 128, 0, stream>>>(statsb, g0, be0, ssb);

  // ---- layer 1 (BN0+ReLU folded into GEMM staging)
  gemm_dual<128><<<(NN + 63) / 64, 256, 0, stream>>>(hpre, Wl1, Wr1, ssb, tlb, tr);
  hipMemsetAsync(agg, 0, AGG_B, stream);
  hipMemsetAsync(statsb, 0, (size_t)SREP * 256 * 4, stream);
  edge_atomic<128><<<EG128, 256, 0, stream>>>(tlb, srcs, dw, agg);
  combine<128, true><<<NN / 40, 256, 0, stream>>>(agg, tr, invd, b1, hpre, statsb);
  bn_fin<<<1, 128, 0, stream>>>(statsb, g1, be1, ssb);

  // ---- layer 2 (BN1+ReLU folded; F=64 straight to d_out)
  gemm_dual<64><<<(NN + 127) / 128, 256, 0, stream>>>(hpre, Wl2, Wr2, ssb, tlb, tr);
  hipMemsetAsync(agg, 0, AGG_B / 2, stream);
  edge_atomic<64><<<EG64, 256, 0, stream>>>(tlb, srcs, dw, agg);
  combine<64, false><<<NN / 40, 256, 0, stream>>>(agg, tr, invd, b2, out, nullptr);
}

// Round 10
// 746.481 us; speedup vs baseline: 2.6716x; 1.1596x over previous
//
#include <hip/hip_runtime.h>
#include <hip/hip_bf16.h>

#define NN 50000
#define EE 600000
#define SREP 64   // stats replicas (atomic decontention)

#if __has_builtin(__builtin_amdgcn_global_atomic_fadd_v2bf16)
#define USE_PK 1
typedef short bf2v __attribute__((ext_vector_type(2)));
#else
#define USE_PK 0
#endif

typedef short bf16x8 __attribute__((ext_vector_type(8)));
typedef float f32x4 __attribute__((ext_vector_type(4)));

__device__ inline ushort f2bf(float x) {  // round-to-nearest-even bf16
  unsigned u = __float_as_uint(x);
  u = (u + 0x7fffu + ((u >> 16) & 1u)) >> 16;
  return (ushort)u;
}
__device__ inline float bflo(uint t) { return __uint_as_float(t << 16); }
__device__ inline float bfhi(uint t) { return __uint_as_float(t & 0xffff0000u); }

// ---------- graph preprocessing ----------
__global__ void count2_k(const int* __restrict__ ei, int* __restrict__ cnt_s,
                         int* __restrict__ cnt_d) {
  int e = blockIdx.x * 256 + threadIdx.x;
  if (e < EE) {
    atomicAdd(&cnt_s[ei[e]], 1);
    atomicAdd(&cnt_d[ei[EE + e]], 1);
  }
}

// exclusive prefix of cnt -> cur (single block)
__global__ void scan_k(const int* __restrict__ cnt, int* __restrict__ cur) {
  __shared__ int ls[1024];
  const int t = threadIdx.x;
  const int STRIP = (NN + 1023) >> 10;  // 49
  int i0 = t * STRIP;
  int i1 = min(i0 + STRIP, NN);
  int s = 0;
  for (int i = i0; i < i1; ++i) s += cnt[i];
  ls[t] = s;
  __syncthreads();
  for (int off = 1; off < 1024; off <<= 1) {
    int v = (t >= off) ? ls[t - off] : 0;
    __syncthreads();
    ls[t] += v;
    __syncthreads();
  }
  int run = (t == 0) ? 0 : ls[t - 1];
  for (int i = i0; i < i1; ++i) { cur[i] = run; run += cnt[i]; }
}

__global__ void invd_k(const int* __restrict__ cnt_d, float* __restrict__ invd) {
  int n = blockIdx.x * 256 + threadIdx.x;
  if (n < NN) invd[n] = 1.0f / (float)max(cnt_d[n], 1);
}

// CSC order (grouped by src): one 16B record per edge {src, dst, wbits, 0}
__global__ void fill_csc_k(const int* __restrict__ ei, const float* __restrict__ ew,
                           int* __restrict__ cur_s, int4* __restrict__ e4) {
  int e = blockIdx.x * 256 + threadIdx.x;
  if (e < EE) {
    int s = ei[e], d = ei[EE + e];
    int pc = atomicAdd(&cur_s[s], 1);
    int4 v;
    v.x = s; v.y = d; v.z = __float_as_int(ew[e]); v.w = 0;
    e4[pc] = v;
  }
}

// ---------- MFMA dual GEMM: Tl = bnrelu(H)@Wl (bf16 chunked), Tr = ..@Wr ----
// 64 nodes/block, 16x16x32 bf16 MFMA. Two phases (Wl then Wr) keep LDS <=48KB.
// Swizzle: 16B chunk c of row r stored at slot (c+r)&15 -> 2-way conflict (free).
template <int F>
__global__ __launch_bounds__(256) void gemm_mfma(
    const float* __restrict__ H, const float* __restrict__ Wl,
    const float* __restrict__ Wr, const float* __restrict__ ss,
    ushort* __restrict__ Tlb, float* __restrict__ Tr) {
  constexpr int KLOG = (F == 128) ? 7 : 6;
  __shared__ ushort Wt[F * 128];   // [n][k] bf16 swizzled
  __shared__ ushort Hs[64 * 128];  // [m][k] bf16 swizzled
  const int tid = threadIdx.x;
  const int nb = blockIdx.x * 64;

  // ---- stage H tile (BN affine + relu + bf16 convert)
  for (int i = tid; i < 64 * 32; i += 256) {
    int m = i >> 5, kq = i & 31;  // kq = float4 index, k = kq*4
    int node = nb + m;
    float4 hv = {0.f, 0.f, 0.f, 0.f};
    if (node < NN) hv = ((const float4*)H)[(size_t)node * 32 + kq];
    if (ss) {
      int gk = kq * 4;
      hv.x = fmaxf(fmaf(hv.x, ss[gk + 0], ss[128 + gk + 0]), 0.f);
      hv.y = fmaxf(fmaf(hv.y, ss[gk + 1], ss[128 + gk + 1]), 0.f);
      hv.z = fmaxf(fmaf(hv.z, ss[gk + 2], ss[128 + gk + 2]), 0.f);
      hv.w = fmaxf(fmaf(hv.w, ss[gk + 3], ss[128 + gk + 3]), 0.f);
    }
    int c = kq >> 1;
    int base = m * 128 + (((c + m) & 15) << 3) + (kq & 1) * 4;
    ushort4 u4 = {f2bf(hv.x), f2bf(hv.y), f2bf(hv.z), f2bf(hv.w)};
    *(ushort4*)&Hs[base] = u4;
  }
  __syncthreads();

  const int lane = tid & 63;
  const int w = tid >> 6;       // wave = node subtile
  const int col = lane & 15;
  const int quad = lane >> 4;
  const int m = w * 16 + col;   // A row (local)

  // preload A fragments for the 4 K-steps
  bf16x8 afrag[4];
#pragma unroll
  for (int s = 0; s < 4; ++s) {
    int c = s * 4 + quad;
    afrag[s] = *(const bf16x8*)&Hs[m * 128 + (((c + m) & 15) << 3)];
  }

  for (int phase = 0; phase < 2; ++phase) {
    const float* W = phase ? Wr : Wl;
    __syncthreads();  // protect Wt reuse across phases
    for (int i = tid; i < F * 128; i += 256) {
      int n = i & (F - 1);
      int k = i >> KLOG;
      float v = W[k * F + n];
      Wt[n * 128 + ((((k >> 3) + n) & 15) << 3) + (k & 7)] = f2bf(v);
    }
    __syncthreads();
#pragma unroll 2
    for (int ct = 0; ct < F / 16; ++ct) {
      int n = ct * 16 + col;
      f32x4 acc = {0.f, 0.f, 0.f, 0.f};
#pragma unroll
      for (int s = 0; s < 4; ++s) {
        int c = s * 4 + quad;
        bf16x8 b = *(const bf16x8*)&Wt[n * 128 + (((c + n) & 15) << 3)];
        acc = __builtin_amdgcn_mfma_f32_16x16x32_bf16(afrag[s], b, acc, 0, 0, 0);
      }
      int nodeb = nb + w * 16 + quad * 4;
#pragma unroll
      for (int r = 0; r < 4; ++r) {
        int node = nodeb + r;
        if (node < NN) {
          int cc = ct * 16 + col;
          if (phase == 0) {
            Tlb[(size_t)(cc >> 5) * NN * 32 + (size_t)node * 32 + (cc & 31)] = f2bf(acc[r]);
          } else {
            Tr[(size_t)node * F + cc] = acc[r];
          }
        }
      }
    }
  }
}

// ---------- edge-parallel aggregation via HW pk-bf16 atomics ----------
// At the measured atomic roofline (~0.94 RMW/clk/slice) — structural floor.
template <int F>
__global__ __launch_bounds__(256, 8) void edge_atomic(
    const ushort* __restrict__ Tlb, const int4* __restrict__ e4,
    void* __restrict__ agg) {
  constexpr int L = F / 2;
  int gid = blockIdx.x * 256 + threadIdx.x;
  int e = gid / L;
  int cp = gid % L;
  if (e >= EE) return;
  int4 p = e4[e];
  float w = __int_as_float(p.z);
  int chunk = cp >> 4, coff = cp & 15;
  uint t = ((const uint*)Tlb)[(size_t)chunk * NN * 16 + (size_t)p.x * 16 + coff];
  float f0 = w * bflo(t);
  float f1 = w * bfhi(t);
#if USE_PK
  bf2v v;
  v.x = (short)f2bf(f0);
  v.y = (short)f2bf(f1);
  __builtin_amdgcn_global_atomic_fadd_v2bf16((bf2v*)((char*)agg + ((size_t)p.y * L + cp) * 4), v);
#else
  float* a = (float*)agg + ((size_t)p.y * L + cp) * 2;
  atomicAdd(a, f0);
  atomicAdd(a + 1, f1);
#endif
}

// ---------- combine: out = agg*invd + Tr + bias (+BN stats, SREP slots) ----
template <int F, bool STATS>
__global__ __launch_bounds__(256, 8) void combine(
    const void* __restrict__ agg, const float* __restrict__ Tr,
    const float* __restrict__ invd, const float* __restrict__ bias,
    float* __restrict__ out, float* __restrict__ statsb) {
  constexpr int L = F / 2;
  constexpr int NPI = 256 / L;
  constexpr int NPB = 40;  // 50000/40 = 1250 blocks exact
  const int tid = threadIdx.x;
  const int cp = tid % L;
  const int c = 2 * cp;
  const int nl = tid / L;
  const int n0 = blockIdx.x * NPB;
  const float bx = bias[c], by = bias[c + 1];
  float2 S = {0.f, 0.f}, Q = {0.f, 0.f};
#pragma unroll
  for (int it = 0; it < NPB / NPI; ++it) {
    int n = n0 + it * NPI + nl;
    float a0, a1;
#if USE_PK
    uint t = ((const uint*)agg)[(size_t)n * L + cp];
    a0 = bflo(t);
    a1 = bfhi(t);
#else
    float2 af = ((const float2*)agg)[(size_t)n * L + cp];
    a0 = af.x;
    a1 = af.y;
#endif
    float iv = invd[n];
    float2 tr = *(const float2*)(Tr + (size_t)n * F + c);
    float2 v;
    v.x = fmaf(a0, iv, tr.x + bx);
    v.y = fmaf(a1, iv, tr.y + by);
    *(float2*)(out + (size_t)n * F + c) = v;
    if constexpr (STATS) {
      S.x += v.x; S.y += v.y;
      Q.x += v.x * v.x; Q.y += v.y * v.y;
    }
  }
  if constexpr (STATS) {
    __shared__ float2 sS[4][L];
    __shared__ float2 sQ[4][L];
    const int wid = tid >> 6, wl = tid & 63;
    if constexpr (L == 64) {
      sS[wid][wl] = S;
      sQ[wid][wl] = Q;
    } else {
      S.x += __shfl_xor(S.x, 32, 64); S.y += __shfl_xor(S.y, 32, 64);
      Q.x += __shfl_xor(Q.x, 32, 64); Q.y += __shfl_xor(Q.y, 32, 64);
      if (wl < 32) { sS[wid][wl] = S; sQ[wid][wl] = Q; }
    }
    __syncthreads();
    if (tid < L) {
      float2 Sa = sS[0][tid], Qa = sQ[0][tid];
#pragma unroll
      for (int w2 = 1; w2 < 4; ++w2) {
        Sa.x += sS[w2][tid].x; Sa.y += sS[w2][tid].y;
        Qa.x += sQ[w2][tid].x; Qa.y += sQ[w2][tid].y;
      }
      float* sb = statsb + (size_t)(blockIdx.x & (SREP - 1)) * 256;
      int col = 2 * tid;
      atomicAdd(&sb[col], Sa.x);
      atomicAdd(&sb[col + 1], Sa.y);
      atomicAdd(&sb[128 + col], Qa.x);
      atomicAdd(&sb[128 + col + 1], Qa.y);
    }
  }
}

// ---------- BN finalize ----------
__global__ void bn_fin(const float* __restrict__ statsb, const float* __restrict__ gamma,
                       const float* __restrict__ beta, float* __restrict__ ss) {
  int f = threadIdx.x;
  float sum = 0.f, sq = 0.f;
#pragma unroll 8
  for (int r = 0; r < SREP; ++r) {
    sum += statsb[r * 256 + f];
    sq  += statsb[r * 256 + 128 + f];
  }
  float mu = sum * (1.0f / (float)NN);
  float ex2 = sq * (1.0f / (float)NN);
  float var = ex2 - mu * mu;
  float sc = gamma[f] * rsqrtf(var + 1e-5f);
  ss[f] = sc;
  ss[128 + f] = beta[f] - mu * sc;
}

extern "C" void kernel_launch(void* const* d_in, const int* in_sizes, int n_in,
                              void* d_out, int out_size, void* d_ws, size_t ws_size,
                              hipStream_t stream) {
  (void)in_sizes; (void)n_in; (void)out_size; (void)ws_size;
  const float* x   = (const float*)d_in[0];
  const int*   ei  = (const int*)d_in[1];
  const float* ew  = (const float*)d_in[2];
  const float* Wl0 = (const float*)d_in[3];
  const float* Wr0 = (const float*)d_in[4];
  const float* b0  = (const float*)d_in[5];
  const float* Wl1 = (const float*)d_in[6];
  const float* Wr1 = (const float*)d_in[7];
  const float* b1  = (const float*)d_in[8];
  const float* Wl2 = (const float*)d_in[9];
  const float* Wr2 = (const float*)d_in[10];
  const float* b2  = (const float*)d_in[11];
  const float* g0  = (const float*)d_in[12];
  const float* be0 = (const float*)d_in[13];
  const float* g1  = (const float*)d_in[14];
  const float* be1 = (const float*)d_in[15];
  float* out = (float*)d_out;

  size_t off = 0;
  auto alloc = [&](size_t b) -> void* {
    void* p = (char*)d_ws + off;
    off += (b + 255) & ~(size_t)255;
    return p;
  };
  ushort* tlb  = (ushort*)alloc((size_t)NN * 128 * 2);  // 12.8 MB
  float* tr    = (float*)alloc((size_t)NN * 128 * 4);   // 25.6 MB
  float* hpre  = (float*)alloc((size_t)NN * 128 * 4);   // 25.6 MB
#if USE_PK
  const size_t AGG_B = (size_t)NN * 128 * 2;            // bf16 agg
#else
  const size_t AGG_B = (size_t)NN * 128 * 4;            // f32 agg
#endif
  void* agg    = alloc((size_t)NN * 128 * 4);           // 25.6 MB
  int4* e4     = (int4*)alloc((size_t)EE * 16);         // 9.6 MB
  int*  cnts   = (int*)alloc((size_t)NN * 2 * 4);       // cnt_s | cnt_d contiguous
  int*  cnt_s  = cnts;
  int*  cnt_d  = cnts + NN;
  int*  cur_s  = (int*)alloc((size_t)NN * 4);
  float* invd  = (float*)alloc((size_t)NN * 4);
  float* statsb = (float*)alloc((size_t)SREP * 256 * 4);
  float* ssb   = (float*)alloc(256 * 4);

  const int EB = (EE + 255) / 256;
  const int GEMMB = (NN + 63) / 64;  // 782

  // ---- prep
  hipMemsetAsync(cnts, 0, (size_t)NN * 2 * 4, stream);
  count2_k<<<EB, 256, 0, stream>>>(ei, cnt_s, cnt_d);
  scan_k<<<1, 1024, 0, stream>>>(cnt_s, cur_s);
  invd_k<<<(NN + 255) / 256, 256, 0, stream>>>(cnt_d, invd);
  fill_csc_k<<<EB, 256, 0, stream>>>(ei, ew, cur_s, e4);

  const int EG128 = (int)(((size_t)EE * 64 + 255) / 256);
  const int EG64  = (int)(((size_t)EE * 32 + 255) / 256);

  // ---- layer 0
  gemm_mfma<128><<<GEMMB, 256, 0, stream>>>(x, Wl0, Wr0, nullptr, tlb, tr);
  hipMemsetAsync(agg, 0, AGG_B, stream);
  hipMemsetAsync(statsb, 0, (size_t)SREP * 256 * 4, stream);
  edge_atomic<128><<<EG128, 256, 0, stream>>>(tlb, e4, agg);
  combine<128, true><<<NN / 40, 256, 0, stream>>>(agg, tr, invd, b0, hpre, statsb);
  bn_fin<<<1, 128, 0, stream>>>(statsb, g0, be0, ssb);

  // ---- layer 1 (BN0+ReLU folded into gemm staging)
  gemm_mfma<128><<<GEMMB, 256, 0, stream>>>(hpre, Wl1, Wr1, ssb, tlb, tr);
  hipMemsetAsync(agg, 0, AGG_B, stream);
  hipMemsetAsync(statsb, 0, (size_t)SREP * 256 * 4, stream);
  edge_atomic<128><<<EG128, 256, 0, stream>>>(tlb, e4, agg);
  combine<128, true><<<NN / 40, 256, 0, stream>>>(agg, tr, invd, b1, hpre, statsb);
  bn_fin<<<1, 128, 0, stream>>>(statsb, g1, be1, ssb);

  // ---- layer 2 (BN1+ReLU folded; F=64 straight to d_out)
  gemm_mfma<64><<<GEMMB, 256, 0, stream>>>(hpre, Wl2, Wr2, ssb, tlb, tr);
  hipMemsetAsync(agg, 0, AGG_B / 2, stream);
  edge_atomic<64><<<EG64, 256, 0, stream>>>(tlb, e4, agg);
  combine<64, false><<<NN / 40, 256, 0, stream>>>(agg, tr, invd, b2, out, nullptr);
}